// Round 1
// baseline (4313.189 us; speedup 1.0000x reference)
//
#include <hip/hip_runtime.h>
#include <hip/hip_bf16.h>
#include <math.h>

#define HD 1024   // hidden
#define FD 4096   // ffn
#define NE 8      // experts
#define CAP 4096  // per-expert bucket capacity (max tokens)

typedef __attribute__((ext_vector_type(8))) short short8;
typedef __attribute__((ext_vector_type(4))) float f32x4;

__device__ inline unsigned short f2b(float f) {
    union { float f; unsigned u; } v; v.f = f;
    unsigned r = v.u + 0x7FFF + ((v.u >> 16) & 1);   // round-to-nearest-even
    return (unsigned short)(r >> 16);
}

// ---------------- gating: one wave per token ----------------
__global__ __launch_bounds__(256) void gate_kernel(
    const float* __restrict__ x, const float* __restrict__ Wg,
    const float* __restrict__ bg, int* __restrict__ cnt,
    int* __restrict__ btok, float* __restrict__ bw,
    int* __restrict__ tokSlot, int T)
{
    int wave = threadIdx.x >> 6;
    int lane = threadIdx.x & 63;
    int t = blockIdx.x * 4 + wave;
    if (t >= T) return;

    float part[NE];
#pragma unroll
    for (int e = 0; e < NE; e++) part[e] = 0.f;
    const float* xr = x + (size_t)t * HD;
#pragma unroll 4
    for (int j = 0; j < 16; j++) {
        int h = lane + 64 * j;
        float xv = xr[h];
        const float* wr = Wg + h * NE;
#pragma unroll
        for (int e = 0; e < NE; e++) part[e] += xv * wr[e];
    }
#pragma unroll
    for (int e = 0; e < NE; e++) {
        float v = part[e];
        for (int off = 32; off >= 1; off >>= 1) v += __shfl_xor(v, off, 64);
        part[e] = v;
    }
    if (lane == 0) {
        float lg[NE];
#pragma unroll
        for (int e = 0; e < NE; e++) lg[e] = part[e] + bg[e];
        int i0 = 0;
        for (int e = 1; e < NE; e++) if (lg[e] > lg[i0]) i0 = e;
        int i1 = -1;
        for (int e = 0; e < NE; e++) {
            if (e == i0) continue;
            if (i1 < 0 || lg[e] > lg[i1]) i1 = e;
        }
        // renormalized top-2 softmax weights: exp shift by top logit; Z cancels
        float e1 = expf(lg[i1] - lg[i0]);
        float s = 1.0f + e1;
        float w0 = 1.0f / s, w1 = e1 / s;
        int p0 = atomicAdd(&cnt[i0], 1);
        int p1 = atomicAdd(&cnt[i1], 1);
        btok[i0 * CAP + p0] = t; bw[i0 * CAP + p0] = w0;
        btok[i1 * CAP + p1] = t; bw[i1 * CAP + p1] = w1;
        tokSlot[t * 2 + 0] = i0 * CAP + p0;   // CAP=4096=2^12 -> e = slot>>12, pos = slot&4095
        tokSlot[t * 2 + 1] = i1 * CAP + p1;
    }
}

// ---------------- prefix-sum of expert counts ----------------
__global__ void scan_kernel(const int* __restrict__ cnt, int* __restrict__ offs)
{
    if (threadIdx.x == 0) {
        int acc = 0;
        for (int e = 0; e < NE; e++) { offs[e] = acc; acc += cnt[e]; }
    }
}

// ---------------- GEMM1: h = silu(x@W1) * (x@W3), grouped per expert ----------------
// tile: 128 tokens x 128 F, BK=64, 256 threads (4 waves, 2x2 of 64x64)
__global__ __launch_bounds__(256, 2) void gemm1_kernel(
    const float* __restrict__ x, const float* __restrict__ W1,
    const float* __restrict__ W3, const int* __restrict__ btok,
    const int* __restrict__ cnt, const int* __restrict__ offs,
    unsigned short* __restrict__ h_buf)
{
    int e = blockIdx.z;
    int ne = cnt[e];
    int m0 = blockIdx.x * 128;
    if (m0 >= ne) return;
    int f0 = blockIdx.y * 128;

    __shared__ unsigned short As[128 * 72];
    __shared__ unsigned short B1s[128 * 72];
    __shared__ unsigned short B3s[128 * 72];

    int tid = threadIdx.x;
    int lane = tid & 63;
    int w = tid >> 6;
    int wm = (w >> 1) * 64, wn = (w & 1) * 64;
    int l15 = lane & 15, quad = lane >> 4;

    f32x4 accG[4][4], accU[4][4];
    f32x4 z = {0.f, 0.f, 0.f, 0.f};
#pragma unroll
    for (int i = 0; i < 4; i++)
#pragma unroll
        for (int j = 0; j < 4; j++) { accG[i][j] = z; accU[i][j] = z; }

    const float* W1e = W1 + (size_t)e * HD * FD;
    const float* W3e = W3 + (size_t)e * HD * FD;
    const int* bt = btok + e * CAP;

    for (int k0 = 0; k0 < HD; k0 += 64) {
        // stage A (gathered tokens): 128 rows x 64 k, fp32 -> bf16
#pragma unroll
        for (int p = 0; p < 8; p++) {
            int idx = p * 256 + tid;          // 2048 float4-groups/4 = row covers
            int row = idx >> 4;               // [0,128)
            int c4 = (idx & 15) * 4;          // [0,64)
            int ridx = m0 + row; if (ridx >= ne) ridx = ne - 1;
            int token = bt[ridx];
            const float4 v = *(const float4*)(x + (size_t)token * HD + k0 + c4);
            ushort4 b;
            b.x = f2b(v.x); b.y = f2b(v.y); b.z = f2b(v.z); b.w = f2b(v.w);
            *(ushort4*)&As[row * 72 + c4] = b;
        }
        // stage B1/B3: 64 k x 128 f, transposed to [f][k]
#pragma unroll
        for (int p = 0; p < 8; p++) {
            int f4 = (tid & 31) * 4;
            int k = (tid >> 5) + p * 8;
            const float4 v1 = *(const float4*)(W1e + (size_t)(k0 + k) * FD + f0 + f4);
            B1s[(f4 + 0) * 72 + k] = f2b(v1.x);
            B1s[(f4 + 1) * 72 + k] = f2b(v1.y);
            B1s[(f4 + 2) * 72 + k] = f2b(v1.z);
            B1s[(f4 + 3) * 72 + k] = f2b(v1.w);
            const float4 v3 = *(const float4*)(W3e + (size_t)(k0 + k) * FD + f0 + f4);
            B3s[(f4 + 0) * 72 + k] = f2b(v3.x);
            B3s[(f4 + 1) * 72 + k] = f2b(v3.y);
            B3s[(f4 + 2) * 72 + k] = f2b(v3.z);
            B3s[(f4 + 3) * 72 + k] = f2b(v3.w);
        }
        __syncthreads();
#pragma unroll
        for (int kk = 0; kk < 2; kk++) {
            int kb = kk * 32 + quad * 8;
            short8 af[4], b1f[4], b3f[4];
#pragma unroll
            for (int mt = 0; mt < 4; mt++)
                af[mt] = *(const short8*)&As[(wm + mt * 16 + l15) * 72 + kb];
#pragma unroll
            for (int nt = 0; nt < 4; nt++) {
                b1f[nt] = *(const short8*)&B1s[(wn + nt * 16 + l15) * 72 + kb];
                b3f[nt] = *(const short8*)&B3s[(wn + nt * 16 + l15) * 72 + kb];
            }
#pragma unroll
            for (int mt = 0; mt < 4; mt++)
#pragma unroll
                for (int nt = 0; nt < 4; nt++) {
                    accG[mt][nt] = __builtin_amdgcn_mfma_f32_16x16x32_bf16(af[mt], b1f[nt], accG[mt][nt], 0, 0, 0);
                    accU[mt][nt] = __builtin_amdgcn_mfma_f32_16x16x32_bf16(af[mt], b3f[nt], accU[mt][nt], 0, 0, 0);
                }
        }
        __syncthreads();
    }
    // epilogue: silu(g)*u -> bf16 -> h_buf (compacted rows)
    int base = offs[e] + m0;
#pragma unroll
    for (int mt = 0; mt < 4; mt++) {
#pragma unroll
        for (int r = 0; r < 4; r++) {
            int row = wm + mt * 16 + quad * 4 + r;
            if (m0 + row < ne) {
                size_t rb = (size_t)(base + row) * FD;
#pragma unroll
                for (int nt = 0; nt < 4; nt++) {
                    int col = f0 + wn + nt * 16 + l15;
                    float g = accG[mt][nt][r];
                    float u = accU[mt][nt][r];
                    float h = g / (1.f + expf(-g)) * u;
                    h_buf[rb + col] = f2b(h);
                }
            }
        }
    }
}

// ---------------- GEMM2: contrib = cw * (h @ W2), grouped per expert ----------------
// tile: 128 rows x 128 H, BK=64, K=4096
__global__ __launch_bounds__(256, 2) void gemm2_kernel(
    const unsigned short* __restrict__ h_buf, const float* __restrict__ W2,
    const float* __restrict__ bw, const int* __restrict__ cnt,
    const int* __restrict__ offs, float* __restrict__ contrib)
{
    int e = blockIdx.z;
    int ne = cnt[e];
    int m0 = blockIdx.x * 128;
    if (m0 >= ne) return;
    int h0 = blockIdx.y * 128;

    __shared__ unsigned short As[128 * 72];
    __shared__ unsigned short Bs[128 * 72];

    int tid = threadIdx.x;
    int lane = tid & 63;
    int w = tid >> 6;
    int wm = (w >> 1) * 64, wn = (w & 1) * 64;
    int l15 = lane & 15, quad = lane >> 4;

    f32x4 acc[4][4];
    f32x4 z = {0.f, 0.f, 0.f, 0.f};
#pragma unroll
    for (int i = 0; i < 4; i++)
#pragma unroll
        for (int j = 0; j < 4; j++) acc[i][j] = z;

    const float* W2e = W2 + (size_t)e * FD * HD;
    int obase = offs[e];

    for (int k0 = 0; k0 < FD; k0 += 64) {
        // stage A from h_buf (already bf16): 128 rows x 64 k, 16B loads
#pragma unroll
        for (int p = 0; p < 4; p++) {
            int idx = p * 256 + tid;          // [0,1024)
            int row = idx >> 3;               // [0,128)
            int c8 = (idx & 7) * 8;           // [0,64)
            int ridx = m0 + row; if (ridx >= ne) ridx = ne - 1;
            uint4 v = *(const uint4*)(h_buf + (size_t)(obase + ridx) * FD + k0 + c8);
            *(uint4*)&As[row * 72 + c8] = v;
        }
        // stage B from W2: 64 k x 128 h, transposed to [h][k]
#pragma unroll
        for (int p = 0; p < 8; p++) {
            int h4 = (tid & 31) * 4;
            int k = (tid >> 5) + p * 8;
            const float4 v = *(const float4*)(W2e + (size_t)(k0 + k) * HD + h0 + h4);
            Bs[(h4 + 0) * 72 + k] = f2b(v.x);
            Bs[(h4 + 1) * 72 + k] = f2b(v.y);
            Bs[(h4 + 2) * 72 + k] = f2b(v.z);
            Bs[(h4 + 3) * 72 + k] = f2b(v.w);
        }
        __syncthreads();
#pragma unroll
        for (int kk = 0; kk < 2; kk++) {
            int kb = kk * 32 + quad * 8;
            short8 af[4], bf[4];
#pragma unroll
            for (int mt = 0; mt < 4; mt++)
                af[mt] = *(const short8*)&As[(wm + mt * 16 + l15) * 72 + kb];
#pragma unroll
            for (int nt = 0; nt < 4; nt++)
                bf[nt] = *(const short8*)&Bs[(wn + nt * 16 + l15) * 72 + kb];
#pragma unroll
            for (int mt = 0; mt < 4; mt++)
#pragma unroll
                for (int nt = 0; nt < 4; nt++)
                    acc[mt][nt] = __builtin_amdgcn_mfma_f32_16x16x32_bf16(af[mt], bf[nt], acc[mt][nt], 0, 0, 0);
        }
        __syncthreads();
    }
    int base = obase + m0;
#pragma unroll
    for (int mt = 0; mt < 4; mt++) {
#pragma unroll
        for (int r = 0; r < 4; r++) {
            int row = wm + mt * 16 + quad * 4 + r;
            if (m0 + row < ne) {
                float wgt = bw[e * CAP + m0 + row];
                size_t rb = (size_t)(base + row) * HD;
#pragma unroll
                for (int nt = 0; nt < 4; nt++) {
                    int col = h0 + wn + nt * 16 + l15;
                    contrib[rb + col] = acc[mt][nt][r] * wgt;
                }
            }
        }
    }
}

// ---------------- combine: out[t] = contrib[r0] + contrib[r1] ----------------
__global__ __launch_bounds__(256) void combine_kernel(
    const float* __restrict__ contrib, const int* __restrict__ tokSlot,
    const int* __restrict__ offs, float* __restrict__ out)
{
    int t = blockIdx.x;
    int i = threadIdx.x;            // 256 threads x float4 = 1024 floats
    int s0 = tokSlot[t * 2 + 0];
    int s1 = tokSlot[t * 2 + 1];
    int r0 = offs[s0 >> 12] + (s0 & (CAP - 1));
    int r1 = offs[s1 >> 12] + (s1 & (CAP - 1));
    float4 a = *(const float4*)(contrib + (size_t)r0 * HD + i * 4);
    float4 b = *(const float4*)(contrib + (size_t)r1 * HD + i * 4);
    float4 o;
    o.x = a.x + b.x; o.y = a.y + b.y; o.z = a.z + b.z; o.w = a.w + b.w;
    *(float4*)(out + (size_t)t * HD + i * 4) = o;
}

extern "C" void kernel_launch(void* const* d_in, const int* in_sizes, int n_in,
                              void* d_out, int out_size, void* d_ws, size_t ws_size,
                              hipStream_t stream)
{
    const float* x  = (const float*)d_in[0];
    const float* Wg = (const float*)d_in[1];
    const float* bg = (const float*)d_in[2];
    const float* W1 = (const float*)d_in[3];
    const float* W3 = (const float*)d_in[4];
    const float* W2 = (const float*)d_in[5];
    float* out = (float*)d_out;
    int T = in_sizes[0] / HD;   // 4096 tokens

    // ws layout (~97 MB needed)
    char* ws = (char*)d_ws;
    int*   cnt     = (int*)ws;                              // 8 ints
    int*   offs    = cnt + 8;                               // 8 ints
    int*   btok    = (int*)(ws + 256);                      // 8*4096 ints  (128 KB)
    float* bw      = (float*)(ws + 256 + 131072);           // 8*4096 floats (128 KB)
    int*   tokSlot = (int*)(ws + 256 + 262144);             // 4096*2 ints  (32 KB)
    unsigned short* h_buf = (unsigned short*)(ws + (1 << 20));            // 8192*4096 bf16 = 64 MB
    float* contrib = (float*)(ws + (1 << 20) + ((size_t)64 << 20));       // 8192*1024 f32 = 32 MB

    hipMemsetAsync(cnt, 0, 8 * sizeof(int), stream);

    gate_kernel<<<(T + 3) / 4, 256, 0, stream>>>(x, Wg, bg, cnt, btok, bw, tokSlot, T);
    scan_kernel<<<1, 64, 0, stream>>>(cnt, offs);

    dim3 g1(32, FD / 128, NE);   // m-tiles x f-tiles x experts (inactive m-tiles early-exit)
    gemm1_kernel<<<g1, 256, 0, stream>>>(x, W1, W3, btok, cnt, offs, h_buf);

    dim3 g2(32, HD / 128, NE);
    gemm2_kernel<<<g2, 256, 0, stream>>>(h_buf, W2, bw, cnt, offs, contrib);

    combine_kernel<<<T, 256, 0, stream>>>(contrib, tokSlot, offs, out);
}

// Round 2
// 1345.678 us; speedup vs baseline: 3.2052x; 3.2052x over previous
//
#include <hip/hip_runtime.h>
#include <hip/hip_bf16.h>
#include <math.h>

#define HD 1024   // hidden
#define FD 4096   // ffn
#define NE 8      // experts
#define CAP 4096  // per-expert bucket capacity

typedef __attribute__((ext_vector_type(8))) short short8;
typedef __attribute__((ext_vector_type(4))) float f32x4;

__device__ inline unsigned short f2b(float f) {
    union { float f; unsigned u; } v; v.f = f;
    unsigned r = v.u + 0x7FFF + ((v.u >> 16) & 1);   // round-to-nearest-even
    return (unsigned short)(r >> 16);
}

__device__ inline void gll16(const void* g, void* l) {
    __builtin_amdgcn_global_load_lds(
        (const __attribute__((address_space(1))) unsigned int*)g,
        (__attribute__((address_space(3))) unsigned int*)l, 16, 0, 0);
}

// ---------------- x fp32 -> bf16 ----------------
__global__ __launch_bounds__(256) void convx_kernel(const float* __restrict__ x,
                                                    unsigned short* __restrict__ xbf)
{
    int i = blockIdx.x * 256 + threadIdx.x;   // each handles 4 elements
    float4 v = *(const float4*)(x + (size_t)i * 4);
    ushort4 b; b.x = f2b(v.x); b.y = f2b(v.y); b.z = f2b(v.z); b.w = f2b(v.w);
    *(ushort4*)(xbf + (size_t)i * 4) = b;
}

// ---------------- transpose+convert: in [R][C] fp32 -> out [C][R] bf16, swizzled ----------------
// out row c: within each 64-wide k-window, 16B chunk j stored at position j ^ (c&7)
__global__ __launch_bounds__(256) void transpose_kernel(const float* __restrict__ in,
                                                        unsigned short* __restrict__ out,
                                                        int R, int C)
{
    __shared__ unsigned short Ls[64 * 72];
    int t = threadIdx.x;
    int r0 = blockIdx.x * 64, c0 = blockIdx.y * 64;
    const float* ip = in + (size_t)blockIdx.z * R * C;
    unsigned short* op = out + (size_t)blockIdx.z * R * C;

    int rl = t >> 4, c4 = (t & 15) * 4;
#pragma unroll
    for (int p = 0; p < 4; p++) {
        int r = p * 16 + rl;
        float4 v = *(const float4*)(ip + (size_t)(r0 + r) * C + c0 + c4);
        Ls[(c4 + 0) * 72 + r] = f2b(v.x);
        Ls[(c4 + 1) * 72 + r] = f2b(v.y);
        Ls[(c4 + 2) * 72 + r] = f2b(v.z);
        Ls[(c4 + 3) * 72 + r] = f2b(v.w);
    }
    __syncthreads();
    int c = t >> 2, j2 = (t & 3) * 2;
    int s = c & 7;
#pragma unroll
    for (int q = 0; q < 2; q++) {
        int j = j2 + q;
        uint4 v = *(const uint4*)&Ls[c * 72 + j * 8];
        *(uint4*)(op + (size_t)(c0 + c) * R + r0 + ((j ^ s) * 8)) = v;
    }
}

// ---------------- gating: one wave per token ----------------
__global__ __launch_bounds__(256) void gate_kernel(
    const float* __restrict__ x, const float* __restrict__ Wg,
    const float* __restrict__ bg, int* __restrict__ cnt,
    int* __restrict__ btok, float* __restrict__ bw,
    int* __restrict__ tokSlot, int T)
{
    int wave = threadIdx.x >> 6;
    int lane = threadIdx.x & 63;
    int t = blockIdx.x * 4 + wave;
    if (t >= T) return;

    float part[NE];
#pragma unroll
    for (int e = 0; e < NE; e++) part[e] = 0.f;
    const float* xr = x + (size_t)t * HD;
#pragma unroll 4
    for (int j = 0; j < 16; j++) {
        int h = lane + 64 * j;
        float xv = xr[h];
        const float* wr = Wg + h * NE;
#pragma unroll
        for (int e = 0; e < NE; e++) part[e] += xv * wr[e];
    }
#pragma unroll
    for (int e = 0; e < NE; e++) {
        float v = part[e];
        for (int off = 32; off >= 1; off >>= 1) v += __shfl_xor(v, off, 64);
        part[e] = v;
    }
    if (lane == 0) {
        float lg[NE];
#pragma unroll
        for (int e = 0; e < NE; e++) lg[e] = part[e] + bg[e];
        int i0 = 0;
        for (int e = 1; e < NE; e++) if (lg[e] > lg[i0]) i0 = e;
        int i1 = -1;
        for (int e = 0; e < NE; e++) {
            if (e == i0) continue;
            if (i1 < 0 || lg[e] > lg[i1]) i1 = e;
        }
        float e1 = expf(lg[i1] - lg[i0]);
        float s = 1.0f + e1;
        float w0 = 1.0f / s, w1 = e1 / s;
        int p0 = atomicAdd(&cnt[i0], 1);
        int p1 = atomicAdd(&cnt[i1], 1);
        btok[i0 * CAP + p0] = t; bw[i0 * CAP + p0] = w0;
        btok[i1 * CAP + p1] = t; bw[i1 * CAP + p1] = w1;
        tokSlot[t * 2 + 0] = i0 * CAP + p0;
        tokSlot[t * 2 + 1] = i1 * CAP + p1;
    }
}

__global__ void scan_kernel(const int* __restrict__ cnt, int* __restrict__ offs)
{
    if (threadIdx.x == 0) {
        int acc = 0;
        for (int e = 0; e < NE; e++) { offs[e] = acc; acc += cnt[e]; }
    }
}

// ---------------- GEMM1: h = silu(x@W1) * (x@W3) ----------------
// 128 tokens x 128 F, BK=64; B via global_load_lds from pre-transposed bf16 weights
__global__ __launch_bounds__(256, 2) void gemm1_kernel(
    const unsigned short* __restrict__ xbf, const unsigned short* __restrict__ Wt1,
    const unsigned short* __restrict__ Wt3, const int* __restrict__ btok,
    const int* __restrict__ cnt, const int* __restrict__ offs,
    unsigned short* __restrict__ h_buf)
{
    int e = blockIdx.z;
    int ne = cnt[e];
    int m0 = blockIdx.x * 128;
    if (m0 >= ne) return;
    int f0 = blockIdx.y * 128;

    __shared__ unsigned short As[128 * 64];
    __shared__ unsigned short B1s[128 * 64];
    __shared__ unsigned short B3s[128 * 64];
    __shared__ int Ts[128];

    int tid = threadIdx.x;
    int lane = tid & 63;
    int w = tid >> 6;
    int wm = (w >> 1) * 64, wn = (w & 1) * 64;
    int l15 = lane & 15, quad = lane >> 4;

    if (tid < 128) {
        int r = m0 + tid; if (r >= ne) r = ne - 1;
        Ts[tid] = btok[e * CAP + r];
    }
    __syncthreads();

    // A staging: 4 16B chunks/thread, swizzled LDS stores
    int j = tid & 7;
    const unsigned short* asrc[4];
    int adst[4];
#pragma unroll
    for (int p = 0; p < 4; p++) {
        int row = p * 32 + (tid >> 3);
        asrc[p] = xbf + (size_t)Ts[row] * HD + j * 8;
        adst[p] = row * 64 + ((j ^ (row & 7)) * 8);
    }
    // B staging: 4 global_load_lds per wave per matrix
    const unsigned short* W1e = Wt1 + (size_t)e * HD * FD;
    const unsigned short* W3e = Wt3 + (size_t)e * HD * FD;
    const unsigned short* b1base[4];
    const unsigned short* b3base[4];
    int bdst[4];
#pragma unroll
    for (int q = 0; q < 4; q++) {
        int i = w * 4 + q;
        int fl = i * 8 + (lane >> 3);
        b1base[q] = W1e + (size_t)(f0 + fl) * HD + (lane & 7) * 8;
        b3base[q] = W3e + (size_t)(f0 + fl) * HD + (lane & 7) * 8;
        bdst[q] = i * 512;
    }
    // fragment read offsets (elements), conflict-free via swizzle
    int aoff[2][4], boff[2][4];
#pragma unroll
    for (int kk = 0; kk < 2; kk++) {
        int cidx = kk * 4 + quad;
#pragma unroll
        for (int i = 0; i < 4; i++) {
            int rm = wm + i * 16 + l15;
            aoff[kk][i] = rm * 64 + ((cidx ^ (rm & 7)) * 8);
            int rn = wn + i * 16 + l15;
            boff[kk][i] = rn * 64 + ((cidx ^ (rn & 7)) * 8);
        }
    }

    f32x4 accG[4][4], accU[4][4];
    f32x4 z = {0.f, 0.f, 0.f, 0.f};
#pragma unroll
    for (int i = 0; i < 4; i++)
#pragma unroll
        for (int jj = 0; jj < 4; jj++) { accG[i][jj] = z; accU[i][jj] = z; }

    for (int k0 = 0; k0 < HD; k0 += 64) {
#pragma unroll
        for (int p = 0; p < 4; p++) {
            uint4 v = *(const uint4*)(asrc[p] + k0);
            *(uint4*)&As[adst[p]] = v;
        }
#pragma unroll
        for (int q = 0; q < 4; q++) {
            gll16(b1base[q] + k0, &B1s[bdst[q]]);
            gll16(b3base[q] + k0, &B3s[bdst[q]]);
        }
        __syncthreads();
#pragma unroll
        for (int kk = 0; kk < 2; kk++) {
            short8 af[4], b1f[4], b3f[4];
#pragma unroll
            for (int mt = 0; mt < 4; mt++) af[mt] = *(const short8*)&As[aoff[kk][mt]];
#pragma unroll
            for (int nt = 0; nt < 4; nt++) {
                b1f[nt] = *(const short8*)&B1s[boff[kk][nt]];
                b3f[nt] = *(const short8*)&B3s[boff[kk][nt]];
            }
#pragma unroll
            for (int mt = 0; mt < 4; mt++)
#pragma unroll
                for (int nt = 0; nt < 4; nt++) {
                    accG[mt][nt] = __builtin_amdgcn_mfma_f32_16x16x32_bf16(af[mt], b1f[nt], accG[mt][nt], 0, 0, 0);
                    accU[mt][nt] = __builtin_amdgcn_mfma_f32_16x16x32_bf16(af[mt], b3f[nt], accU[mt][nt], 0, 0, 0);
                }
        }
        __syncthreads();
    }
    // epilogue: silu(g)*u -> bf16 -> h_buf, pre-swizzled for gemm2's A staging
    int base = offs[e] + m0;
#pragma unroll
    for (int mt = 0; mt < 4; mt++) {
#pragma unroll
        for (int r = 0; r < 4; r++) {
            int rowl = wm + mt * 16 + quad * 4 + r;
            if (m0 + rowl < ne) {
                int key = rowl & 7;   // m0 is a multiple of 128
                size_t rb = (size_t)(base + rowl) * FD;
#pragma unroll
                for (int nt = 0; nt < 4; nt++) {
                    int f = f0 + wn + nt * 16 + l15;
                    float g = accG[mt][nt][r];
                    float u = accU[mt][nt][r];
                    float h = g / (1.f + expf(-g)) * u;
                    int fs = (f & ~63) | (f & 7) | ((((f >> 3) & 7) ^ key) << 3);
                    h_buf[rb + fs] = f2b(h);
                }
            }
        }
    }
}

// ---------------- GEMM2: contrib = cw * (h @ W2) ----------------
__global__ __launch_bounds__(256, 2) void gemm2_kernel(
    const unsigned short* __restrict__ h_buf, const unsigned short* __restrict__ Wt2,
    const float* __restrict__ bw, const int* __restrict__ cnt,
    const int* __restrict__ offs, float* __restrict__ contrib)
{
    int e = blockIdx.z;
    int ne = cnt[e];
    int m0 = blockIdx.x * 128;
    if (m0 >= ne) return;
    int h0 = blockIdx.y * 128;

    __shared__ unsigned short As[128 * 64];
    __shared__ unsigned short Bs[128 * 64];

    int tid = threadIdx.x;
    int lane = tid & 63;
    int w = tid >> 6;
    int wm = (w >> 1) * 64, wn = (w & 1) * 64;
    int l15 = lane & 15, quad = lane >> 4;
    int obase = offs[e];

    const unsigned short* W2e = Wt2 + (size_t)e * FD * HD;
    const unsigned short* abase[4];
    const unsigned short* bbase[4];
    int dst[4];
#pragma unroll
    for (int q = 0; q < 4; q++) {
        int i = w * 4 + q;
        int rowl = i * 8 + (lane >> 3);
        int ridx = m0 + rowl; if (ridx >= ne) ridx = ne - 1;
        abase[q] = h_buf + (size_t)(obase + ridx) * FD + (lane & 7) * 8;
        int hl = i * 8 + (lane >> 3);
        bbase[q] = W2e + (size_t)(h0 + hl) * FD + (lane & 7) * 8;
        dst[q] = i * 512;
    }
    int aoff[2][4], boff[2][4];
#pragma unroll
    for (int kk = 0; kk < 2; kk++) {
        int cidx = kk * 4 + quad;
#pragma unroll
        for (int i = 0; i < 4; i++) {
            int rm = wm + i * 16 + l15;
            aoff[kk][i] = rm * 64 + ((cidx ^ (rm & 7)) * 8);
            int rn = wn + i * 16 + l15;
            boff[kk][i] = rn * 64 + ((cidx ^ (rn & 7)) * 8);
        }
    }

    f32x4 acc[4][4];
    f32x4 z = {0.f, 0.f, 0.f, 0.f};
#pragma unroll
    for (int i = 0; i < 4; i++)
#pragma unroll
        for (int jj = 0; jj < 4; jj++) acc[i][jj] = z;

    for (int k0 = 0; k0 < FD; k0 += 64) {
#pragma unroll
        for (int q = 0; q < 4; q++) {
            gll16(abase[q] + k0, &As[dst[q]]);
            gll16(bbase[q] + k0, &Bs[dst[q]]);
        }
        __syncthreads();
#pragma unroll
        for (int kk = 0; kk < 2; kk++) {
            short8 af[4], bf[4];
#pragma unroll
            for (int mt = 0; mt < 4; mt++) af[mt] = *(const short8*)&As[aoff[kk][mt]];
#pragma unroll
            for (int nt = 0; nt < 4; nt++) bf[nt] = *(const short8*)&Bs[boff[kk][nt]];
#pragma unroll
            for (int mt = 0; mt < 4; mt++)
#pragma unroll
                for (int nt = 0; nt < 4; nt++)
                    acc[mt][nt] = __builtin_amdgcn_mfma_f32_16x16x32_bf16(af[mt], bf[nt], acc[mt][nt], 0, 0, 0);
        }
        __syncthreads();
    }
    int base = obase + m0;
#pragma unroll
    for (int mt = 0; mt < 4; mt++) {
#pragma unroll
        for (int r = 0; r < 4; r++) {
            int rowl = wm + mt * 16 + quad * 4 + r;
            if (m0 + rowl < ne) {
                float wgt = bw[e * CAP + m0 + rowl];
                size_t rb = (size_t)(base + rowl) * HD;
#pragma unroll
                for (int nt = 0; nt < 4; nt++) {
                    int col = h0 + wn + nt * 16 + l15;
                    contrib[rb + col] = acc[mt][nt][r] * wgt;
                }
            }
        }
    }
}

// ---------------- combine ----------------
__global__ __launch_bounds__(256) void combine_kernel(
    const float* __restrict__ contrib, const int* __restrict__ tokSlot,
    const int* __restrict__ offs, float* __restrict__ out)
{
    int t = blockIdx.x;
    int i = threadIdx.x;
    int s0 = tokSlot[t * 2 + 0];
    int s1 = tokSlot[t * 2 + 1];
    int r0 = offs[s0 >> 12] + (s0 & (CAP - 1));
    int r1 = offs[s1 >> 12] + (s1 & (CAP - 1));
    float4 a = *(const float4*)(contrib + (size_t)r0 * HD + i * 4);
    float4 b = *(const float4*)(contrib + (size_t)r1 * HD + i * 4);
    float4 o;
    o.x = a.x + b.x; o.y = a.y + b.y; o.z = a.z + b.z; o.w = a.w + b.w;
    *(float4*)(out + (size_t)t * HD + i * 4) = o;
}

extern "C" void kernel_launch(void* const* d_in, const int* in_sizes, int n_in,
                              void* d_out, int out_size, void* d_ws, size_t ws_size,
                              hipStream_t stream)
{
    const float* x  = (const float*)d_in[0];
    const float* Wg = (const float*)d_in[1];
    const float* bg = (const float*)d_in[2];
    const float* W1 = (const float*)d_in[3];
    const float* W3 = (const float*)d_in[4];
    const float* W2 = (const float*)d_in[5];
    float* out = (float*)d_out;
    int T = in_sizes[0] / HD;   // 4096 tokens

    // ws layout (~304 MB)
    char* ws = (char*)d_ws;
    int*   cnt     = (int*)ws;
    int*   offs    = cnt + 8;
    int*   btok    = (int*)(ws + 1024);
    float* bw      = (float*)(ws + 1024 + 131072);
    int*   tokSlot = (int*)(ws + 1024 + 262144);
    unsigned short* xbf = (unsigned short*)(ws + ((size_t)1 << 20));                 // 8 MB
    unsigned short* Wt1 = (unsigned short*)(ws + ((size_t)16 << 20));                // 64 MB
    unsigned short* Wt3 = (unsigned short*)(ws + ((size_t)80 << 20));                // 64 MB
    unsigned short* Wt2 = (unsigned short*)(ws + ((size_t)144 << 20));               // 64 MB
    unsigned short* h_buf = (unsigned short*)(ws + ((size_t)208 << 20));             // 64 MB
    float* contrib = (float*)(ws + ((size_t)272 << 20));                             // 32 MB

    hipMemsetAsync(cnt, 0, 8 * sizeof(int), stream);

    convx_kernel<<<(T * HD) / 1024, 256, 0, stream>>>(x, xbf);
    dim3 tg1(HD / 64, FD / 64, NE);
    transpose_kernel<<<tg1, 256, 0, stream>>>(W1, Wt1, HD, FD);
    transpose_kernel<<<tg1, 256, 0, stream>>>(W3, Wt3, HD, FD);
    dim3 tg2(FD / 64, HD / 64, NE);
    transpose_kernel<<<tg2, 256, 0, stream>>>(W2, Wt2, FD, HD);

    gate_kernel<<<(T + 3) / 4, 256, 0, stream>>>(x, Wg, bg, cnt, btok, bw, tokSlot, T);
    scan_kernel<<<1, 64, 0, stream>>>(cnt, offs);

    dim3 g1(CAP / 128, FD / 128, NE);
    gemm1_kernel<<<g1, 256, 0, stream>>>(xbf, Wt1, Wt3, btok, cnt, offs, h_buf);

    dim3 g2(CAP / 128, HD / 128, NE);
    gemm2_kernel<<<g2, 256, 0, stream>>>(h_buf, Wt2, bw, cnt, offs, contrib);

    combine_kernel<<<T, 256, 0, stream>>>(contrib, tokSlot, offs, out);
}